// Round 1
// baseline (475.640 us; speedup 1.0000x reference)
//
#include <hip/hip_runtime.h>
#include <hip/hip_bf16.h>
#include <stdint.h>

typedef __attribute__((ext_vector_type(8))) short short8;
typedef __attribute__((ext_vector_type(4))) float f32x4;
typedef __attribute__((ext_vector_type(4))) unsigned int u32x4;

#define NROWS 32768
#define DIM 512
#define KTOT 8192
#define KSPL 7680
#define KNEG -17.6730142508898f   // -log2(e) * (7/2)^2
#define LNEPS 1e-3f

#if __has_builtin(__builtin_amdgcn_exp2f)
#define EXP2F(x) __builtin_amdgcn_exp2f(x)
#else
#define EXP2F(x) exp2f(x)
#endif

__device__ __forceinline__ unsigned short f2bf(float f) {
    unsigned u = __float_as_uint(f);
    u += 0x7fffu + ((u >> 16) & 1u);           // RNE
    return (unsigned short)(u >> 16);
}

// pack two floats -> two bf16 (round-half-up) in one u32 via v_perm
__device__ __forceinline__ unsigned pack_bf2(float a, float b) {
    unsigned ua = __float_as_uint(a) + 0x8000u;
    unsigned ub = __float_as_uint(b) + 0x8000u;
    return __builtin_amdgcn_perm(ub, ua, 0x07060302u); // lo16=ua>>16, hi16=ub>>16
}

// ---------------- prep: weights -> bf16 Bw[o][k], k = g*512+d (spline) | 7680+d (base^T)
__global__ __launch_bounds__(256) void prep_w_k(const float* __restrict__ sw,
                                                const float* __restrict__ bwt,
                                                unsigned short* __restrict__ Bw) {
    const int o = blockIdx.x;
    const int t = threadIdx.x;
    const float* swr = sw + (size_t)o * KSPL;
    unsigned short* br = Bw + (size_t)o * KTOT;
    #pragma unroll
    for (int it = 0; it < 30; ++it) {
        int k = it * 256 + t;
        int d = k & 511, g = k >> 9;
        br[k] = f2bf(swr[d * 15 + g]);
    }
    #pragma unroll
    for (int it = 0; it < 2; ++it) {
        int d = it * 256 + t;
        br[KSPL + d] = f2bf(bwt[(size_t)d * DIM + o]);
    }
}

// ---------------- prep: LayerNorm -> bf16 xn[n][d], one wave per row
__global__ __launch_bounds__(256) void prep_xn_k(const float* __restrict__ x,
                                                 const float* __restrict__ gam,
                                                 const float* __restrict__ bet,
                                                 unsigned short* __restrict__ xn) {
    const int w = threadIdx.x >> 6, l = threadIdx.x & 63;
    const int row = (blockIdx.x << 2) + w;
    const float* xr = x + (size_t)row * DIM + (l << 3);
    float4 a = *(const float4*)xr;
    float4 b = *(const float4*)(xr + 4);
    float s = a.x + a.y + a.z + a.w + b.x + b.y + b.z + b.w;
    float ss = a.x*a.x + a.y*a.y + a.z*a.z + a.w*a.w
             + b.x*b.x + b.y*b.y + b.z*b.z + b.w*b.w;
    #pragma unroll
    for (int m = 32; m >= 1; m >>= 1) {
        s  += __shfl_xor(s,  m, 64);
        ss += __shfl_xor(ss, m, 64);
    }
    const float mean = s * (1.0f / DIM);
    const float var  = ss * (1.0f / DIM) - mean * mean;
    const float rstd = rsqrtf(var + LNEPS);
    float4 g0 = *(const float4*)(gam + (l << 3));
    float4 g1 = *(const float4*)(gam + (l << 3) + 4);
    float4 b0 = *(const float4*)(bet + (l << 3));
    float4 b1 = *(const float4*)(bet + (l << 3) + 4);
    float e[8];
    e[0] = (a.x - mean) * rstd * g0.x + b0.x;
    e[1] = (a.y - mean) * rstd * g0.y + b0.y;
    e[2] = (a.z - mean) * rstd * g0.z + b0.z;
    e[3] = (a.w - mean) * rstd * g0.w + b0.w;
    e[4] = (b.x - mean) * rstd * g1.x + b1.x;
    e[5] = (b.y - mean) * rstd * g1.y + b1.y;
    e[6] = (b.z - mean) * rstd * g1.z + b1.z;
    e[7] = (b.w - mean) * rstd * g1.w + b1.w;
    u32x4 o;
    o[0] = pack_bf2(e[0], e[1]);
    o[1] = pack_bf2(e[2], e[3]);
    o[2] = pack_bf2(e[4], e[5]);
    o[3] = pack_bf2(e[6], e[7]);
    *(u32x4*)(xn + (size_t)row * DIM + (l << 3)) = o;
}

// ---------------- fused KAN GEMM: out[n][o] = sum_k A[n][k]*Bw[o][k] + base_b[o]
// A generated on the fly: k<7680 -> RBF basis of xn; k>=7680 -> relu(x)
__global__ __launch_bounds__(256, 2) void kan_gemm(
    const unsigned short* __restrict__ xn,
    const unsigned short* __restrict__ Bw,
    const float* __restrict__ x,
    const float* __restrict__ bb,
    float* __restrict__ out) {
    // LDS tiles: [row 0..127][slot 0..7] of 8 bf16 (16B); slot s holds k-group s ^ (row&7)
    __shared__ __align__(16) short As[128 * 64];
    __shared__ __align__(16) short Bs[128 * 64];

    const int t = threadIdx.x;
    const int w = t >> 6, l = t & 63;
    const int n0 = (blockIdx.x >> 2) << 7;   // row block (256 of them)
    const int o0 = (blockIdx.x & 3) << 7;    // col block (4 of them)

    const int kkg  = t & 7;    // this thread's fixed k-group for A staging
    const int mrow = t >> 3;   // 0..31 ; m = mrow + 32*i
    const int brow = l >> 3;   // B staging row-in-group
    const int bxor = (l & 7) ^ brow;

    const int wm = (w >> 1) << 6, wn = (w & 1) << 6;
    const int fm = l & 15, fq = l >> 4;

    f32x4 acc[4][4];
    #pragma unroll
    for (int i = 0; i < 4; ++i)
        #pragma unroll
        for (int j = 0; j < 4; ++j)
            acc[i][j] = (f32x4)0.0f;

    #pragma unroll 1
    for (int dsb = 0; dsb < 8; ++dsb) {
        const int d0 = dsb << 6;
        // load this thread's xn slice: 4 m-rows x 8 d-values, reused for all 15 grids
        float xv[4][8];
        #pragma unroll
        for (int i = 0; i < 4; ++i) {
            const int m = mrow + (i << 5);
            u32x4 p = *(const u32x4*)(xn + (size_t)(n0 + m) * DIM + d0 + (kkg << 3));
            #pragma unroll
            for (int q = 0; q < 4; ++q) {
                xv[i][2*q]   = __uint_as_float(p[q] << 16);
                xv[i][2*q+1] = __uint_as_float(p[q] & 0xffff0000u);
            }
        }
        #pragma unroll 1
        for (int g = 0; g < 16; ++g) {
            const int kc = (g < 15) ? ((g << 9) + d0) : (KSPL + d0);
            // ---- B staging: async DMA, 4x global_load_lds_dwordx4 per thread
            #pragma unroll
            for (int i = 0; i < 4; ++i) {
                const int rb = (i << 5) + (w << 3);
                const unsigned short* gp =
                    Bw + (size_t)(o0 + rb + brow) * KTOT + kc + (bxor << 3);
                __builtin_amdgcn_global_load_lds(
                    (const __attribute__((address_space(1))) void*)gp,
                    (__attribute__((address_space(3))) void*)&Bs[rb << 6],
                    16, 0, 0);
            }
            // ---- A staging: compute basis (or relu) -> bf16 -> LDS (xor-swizzled)
            if (g < 15) {
                const float gv = -2.0f + (float)g * (2.0f / 7.0f);
                #pragma unroll
                for (int i = 0; i < 4; ++i) {
                    const int m = mrow + (i << 5);
                    float e[8];
                    #pragma unroll
                    for (int j = 0; j < 8; ++j) {
                        float d = xv[i][j] - gv;
                        e[j] = EXP2F(d * d * KNEG);
                    }
                    u32x4 v;
                    v[0] = pack_bf2(e[0], e[1]);
                    v[1] = pack_bf2(e[2], e[3]);
                    v[2] = pack_bf2(e[4], e[5]);
                    v[3] = pack_bf2(e[6], e[7]);
                    *(u32x4*)&As[((m << 3) | (kkg ^ (m & 7))) << 3] = v;
                }
            } else {
                #pragma unroll
                for (int i = 0; i < 4; ++i) {
                    const int m = mrow + (i << 5);
                    const float* xp = x + (size_t)(n0 + m) * DIM + d0 + (kkg << 3);
                    float4 r0 = *(const float4*)xp;
                    float4 r1 = *(const float4*)(xp + 4);
                    u32x4 v;
                    v[0] = pack_bf2(fmaxf(r0.x, 0.f), fmaxf(r0.y, 0.f));
                    v[1] = pack_bf2(fmaxf(r0.z, 0.f), fmaxf(r0.w, 0.f));
                    v[2] = pack_bf2(fmaxf(r1.x, 0.f), fmaxf(r1.y, 0.f));
                    v[3] = pack_bf2(fmaxf(r1.z, 0.f), fmaxf(r1.w, 0.f));
                    *(u32x4*)&As[((m << 3) | (kkg ^ (m & 7))) << 3] = v;
                }
            }
            __syncthreads();
            // ---- MFMA: 2 k-steps of 32, 4x4 tiles of 16x16
            #pragma unroll
            for (int ks = 0; ks < 2; ++ks) {
                const int kg = (ks << 2) + fq;
                short8 af[4], bf[4];
                #pragma unroll
                for (int mt = 0; mt < 4; ++mt) {
                    const int m = wm + (mt << 4) + fm;
                    af[mt] = *(const short8*)&As[((m << 3) | (kg ^ (m & 7))) << 3];
                }
                #pragma unroll
                for (int nt = 0; nt < 4; ++nt) {
                    const int n = wn + (nt << 4) + fm;
                    bf[nt] = *(const short8*)&Bs[((n << 3) | (kg ^ (n & 7))) << 3];
                }
                #pragma unroll
                for (int mt = 0; mt < 4; ++mt)
                    #pragma unroll
                    for (int nt = 0; nt < 4; ++nt)
                        acc[mt][nt] = __builtin_amdgcn_mfma_f32_16x16x32_bf16(
                            af[mt], bf[nt], acc[mt][nt], 0, 0, 0);
            }
            __syncthreads();
        }
    }
    // ---- epilogue: C layout col=lane&15, row=(lane>>4)*4+reg ; add base_b
    const int rq = fq << 2;
    float bias[4];
    #pragma unroll
    for (int nt = 0; nt < 4; ++nt) bias[nt] = bb[o0 + wn + (nt << 4) + fm];
    #pragma unroll
    for (int mt = 0; mt < 4; ++mt) {
        #pragma unroll
        for (int nt = 0; nt < 4; ++nt) {
            const int gr = n0 + wm + (mt << 4) + rq;
            const int gc = o0 + wn + (nt << 4) + fm;
            #pragma unroll
            for (int r = 0; r < 4; ++r)
                out[(size_t)(gr + r) * DIM + gc] = acc[mt][nt][r] + bias[nt];
        }
    }
}

extern "C" void kernel_launch(void* const* d_in, const int* in_sizes, int n_in,
                              void* d_out, int out_size, void* d_ws, size_t ws_size,
                              hipStream_t stream) {
    const float* x   = (const float*)d_in[0];
    const float* gam = (const float*)d_in[1];
    const float* bet = (const float*)d_in[2];
    const float* sw  = (const float*)d_in[3];
    const float* bwt = (const float*)d_in[4];
    const float* bb  = (const float*)d_in[5];
    float* out = (float*)d_out;

    unsigned short* Bw = (unsigned short*)d_ws;               // 512*8192 bf16 = 8 MB
    unsigned short* xn = Bw + (size_t)DIM * KTOT;             // 32768*512 bf16 = 32 MB

    prep_w_k<<<dim3(512), dim3(256), 0, stream>>>(sw, bwt, Bw);
    prep_xn_k<<<dim3(NROWS / 4), dim3(256), 0, stream>>>(x, gam, bet, xn);
    kan_gemm<<<dim3(1024), dim3(256), 0, stream>>>(xn, Bw, x, bb, out);
}

// Round 2
// 403.852 us; speedup vs baseline: 1.1778x; 1.1778x over previous
//
#include <hip/hip_runtime.h>
#include <hip/hip_bf16.h>
#include <stdint.h>

typedef __attribute__((ext_vector_type(8))) short short8;
typedef __attribute__((ext_vector_type(4))) float f32x4;
typedef __attribute__((ext_vector_type(4))) unsigned int u32x4;

#define NROWS 32768
#define DIM 512
#define KTOT 8192
#define KSPL 7680
#define KNEG -17.6730142508898f   // -log2(e) * (7/2)^2
#define LNEPS 1e-3f

#if __has_builtin(__builtin_amdgcn_exp2f)
#define EXP2F(x) __builtin_amdgcn_exp2f(x)
#else
#define EXP2F(x) exp2f(x)
#endif

__device__ __forceinline__ unsigned short f2bf(float f) {
    unsigned u = __float_as_uint(f);
    u += 0x7fffu + ((u >> 16) & 1u);           // RNE
    return (unsigned short)(u >> 16);
}

// pack two floats -> two bf16 (round-half-up) in one u32 via v_perm
__device__ __forceinline__ unsigned pack_bf2(float a, float b) {
    unsigned ua = __float_as_uint(a) + 0x8000u;
    unsigned ub = __float_as_uint(b) + 0x8000u;
    return __builtin_amdgcn_perm(ub, ua, 0x07060302u); // lo16=ua>>16, hi16=ub>>16
}

// ---------------- prep: weights -> bf16 Bw[o][k], k = g*512+d (spline) | 7680+d (base^T)
// spline reads coalesced (flat k' = d*15+g); scattered 2B writes land in one
// 16KB L2-resident row per block and merge before eviction.
__global__ __launch_bounds__(256) void prep_w_k(const float* __restrict__ sw,
                                                const float* __restrict__ bwt,
                                                unsigned short* __restrict__ Bw) {
    const int o = blockIdx.x;
    const int t = threadIdx.x;
    const float* swr = sw + (size_t)o * KSPL;
    unsigned short* br = Bw + (size_t)o * KTOT;
    #pragma unroll
    for (int it = 0; it < 30; ++it) {
        int k = it * 256 + t;          // = d*15 + g in source order
        float v = swr[k];
        int d = (unsigned)k / 15u;
        int g = k - d * 15;
        br[(g << 9) + d] = f2bf(v);
    }
    #pragma unroll
    for (int it = 0; it < 2; ++it) {
        int d = it * 256 + t;
        br[KSPL + d] = f2bf(bwt[(size_t)d * DIM + o]);
    }
}

// ---------------- prep: LayerNorm -> bf16 xn[n][d], one wave per row
__global__ __launch_bounds__(256) void prep_xn_k(const float* __restrict__ x,
                                                 const float* __restrict__ gam,
                                                 const float* __restrict__ bet,
                                                 unsigned short* __restrict__ xn) {
    const int w = threadIdx.x >> 6, l = threadIdx.x & 63;
    const int row = (blockIdx.x << 2) + w;
    const float* xr = x + (size_t)row * DIM + (l << 3);
    float4 a = *(const float4*)xr;
    float4 b = *(const float4*)(xr + 4);
    float s = a.x + a.y + a.z + a.w + b.x + b.y + b.z + b.w;
    float ss = a.x*a.x + a.y*a.y + a.z*a.z + a.w*a.w
             + b.x*b.x + b.y*b.y + b.z*b.z + b.w*b.w;
    #pragma unroll
    for (int m = 32; m >= 1; m >>= 1) {
        s  += __shfl_xor(s,  m, 64);
        ss += __shfl_xor(ss, m, 64);
    }
    const float mean = s * (1.0f / DIM);
    const float var  = ss * (1.0f / DIM) - mean * mean;
    const float rstd = rsqrtf(var + LNEPS);
    float4 g0 = *(const float4*)(gam + (l << 3));
    float4 g1 = *(const float4*)(gam + (l << 3) + 4);
    float4 b0 = *(const float4*)(bet + (l << 3));
    float4 b1 = *(const float4*)(bet + (l << 3) + 4);
    float e[8];
    e[0] = (a.x - mean) * rstd * g0.x + b0.x;
    e[1] = (a.y - mean) * rstd * g0.y + b0.y;
    e[2] = (a.z - mean) * rstd * g0.z + b0.z;
    e[3] = (a.w - mean) * rstd * g0.w + b0.w;
    e[4] = (b.x - mean) * rstd * g1.x + b1.x;
    e[5] = (b.y - mean) * rstd * g1.y + b1.y;
    e[6] = (b.z - mean) * rstd * g1.z + b1.z;
    e[7] = (b.w - mean) * rstd * g1.w + b1.w;
    u32x4 o;
    o[0] = pack_bf2(e[0], e[1]);
    o[1] = pack_bf2(e[2], e[3]);
    o[2] = pack_bf2(e[4], e[5]);
    o[3] = pack_bf2(e[6], e[7]);
    *(u32x4*)(xn + (size_t)row * DIM + (l << 3)) = o;
}

// ---------------- fused KAN GEMM: out[n][o] = sum_k A[n][k]*Bw[o][k] + base_b[o]
// A generated on the fly: k<7680 -> RBF basis of xn; k>=7680 -> relu(x)
// Block tile 128 rows x 256 cols, 512 threads (8 waves, wave tile 64x64).
// Grid = 256 row-blocks x 2 col-blocks -> basis recompute factor R=2 (was 4).
__global__ __launch_bounds__(512, 4) void kan_gemm(
    const unsigned short* __restrict__ xn,
    const unsigned short* __restrict__ Bw,
    const float* __restrict__ x,
    const float* __restrict__ bb,
    float* __restrict__ out) {
    // LDS: As[row 0..127][slot 0..7 of 8 bf16], slot s holds k-group s ^ (row&7)
    //      Bs[col 0..255][same swizzle]
    __shared__ __align__(16) short As[128 * 64];
    __shared__ __align__(16) short Bs[256 * 64];

    const int t = threadIdx.x;
    const int w = t >> 6, l = t & 63;
    const int n0 = (blockIdx.x >> 1) << 7;   // 256 row blocks
    const int o0 = (blockIdx.x & 1) << 8;    // 2 col blocks

    const int kkg = t & 7;     // A-staging k-group
    const int ar  = t >> 3;    // 0..63 ; rows ar, ar+64

    const int wm = (w >> 2) << 6;            // wave row offset: 0 / 64
    const int wn = (w & 3) << 6;             // wave col offset: 0/64/128/192
    const int fm = l & 15, fq = l >> 4;

    const int brow = l >> 3;                 // B staging row-in-8
    const int bxor = (l & 7) ^ brow;

    f32x4 acc[4][4];
    #pragma unroll
    for (int i = 0; i < 4; ++i)
        #pragma unroll
        for (int j = 0; j < 4; ++j)
            acc[i][j] = (f32x4)0.0f;

    #pragma unroll 1
    for (int dsb = 0; dsb < 8; ++dsb) {
        const int d0 = dsb << 6;
        // xn slice: 2 m-rows x 8 d-values, reused for all 15 grids
        float xv[2][8];
        #pragma unroll
        for (int i = 0; i < 2; ++i) {
            const int m = ar + (i << 6);
            u32x4 p = *(const u32x4*)(xn + (size_t)(n0 + m) * DIM + d0 + (kkg << 3));
            #pragma unroll
            for (int q = 0; q < 4; ++q) {
                xv[i][2*q]   = __uint_as_float(p[q] << 16);
                xv[i][2*q+1] = __uint_as_float(p[q] & 0xffff0000u);
            }
        }
        #pragma unroll 1
        for (int g = 0; g < 16; ++g) {
            const int kc = (g < 15) ? ((g << 9) + d0) : (KSPL + d0);
            // ---- B staging: 256x64 via async DMA, 4 rounds x 8KB
            #pragma unroll
            for (int i = 0; i < 4; ++i) {
                const int rb = (i << 6) + (w << 3);   // wave-uniform
                const unsigned short* gp =
                    Bw + (size_t)(o0 + rb + brow) * KTOT + kc + (bxor << 3);
                __builtin_amdgcn_global_load_lds(
                    (const __attribute__((address_space(1))) void*)gp,
                    (__attribute__((address_space(3))) void*)&Bs[rb << 6],
                    16, 0, 0);
            }
            // ---- A staging: basis (or relu) -> bf16 -> LDS (xor-swizzled)
            if (g < 15) {
                const float gv = -2.0f + (float)g * (2.0f / 7.0f);
                #pragma unroll
                for (int i = 0; i < 2; ++i) {
                    const int m = ar + (i << 6);
                    float e[8];
                    #pragma unroll
                    for (int j = 0; j < 8; ++j) {
                        float d = xv[i][j] - gv;
                        e[j] = EXP2F(d * d * KNEG);
                    }
                    u32x4 v;
                    v[0] = pack_bf2(e[0], e[1]);
                    v[1] = pack_bf2(e[2], e[3]);
                    v[2] = pack_bf2(e[4], e[5]);
                    v[3] = pack_bf2(e[6], e[7]);
                    *(u32x4*)&As[((m << 3) | (kkg ^ (m & 7))) << 3] = v;
                }
            } else {
                #pragma unroll
                for (int i = 0; i < 2; ++i) {
                    const int m = ar + (i << 6);
                    const float* xp = x + (size_t)(n0 + m) * DIM + d0 + (kkg << 3);
                    float4 r0 = *(const float4*)xp;
                    float4 r1 = *(const float4*)(xp + 4);
                    u32x4 v;
                    v[0] = pack_bf2(fmaxf(r0.x, 0.f), fmaxf(r0.y, 0.f));
                    v[1] = pack_bf2(fmaxf(r0.z, 0.f), fmaxf(r0.w, 0.f));
                    v[2] = pack_bf2(fmaxf(r1.x, 0.f), fmaxf(r1.y, 0.f));
                    v[3] = pack_bf2(fmaxf(r1.z, 0.f), fmaxf(r1.w, 0.f));
                    *(u32x4*)&As[((m << 3) | (kkg ^ (m & 7))) << 3] = v;
                }
            }
            __syncthreads();
            // ---- MFMA: 2 k-steps of 32, 4x4 tiles of 16x16 (wave 64x64)
            #pragma unroll
            for (int ks = 0; ks < 2; ++ks) {
                const int kg = (ks << 2) + fq;
                short8 af[4], bf[4];
                #pragma unroll
                for (int mt = 0; mt < 4; ++mt) {
                    const int m = wm + (mt << 4) + fm;
                    af[mt] = *(const short8*)&As[((m << 3) | (kg ^ (m & 7))) << 3];
                }
                #pragma unroll
                for (int nt = 0; nt < 4; ++nt) {
                    const int n = wn + (nt << 4) + fm;
                    bf[nt] = *(const short8*)&Bs[((n << 3) | (kg ^ (n & 7))) << 3];
                }
                #pragma unroll
                for (int mt = 0; mt < 4; ++mt)
                    #pragma unroll
                    for (int nt = 0; nt < 4; ++nt)
                        acc[mt][nt] = __builtin_amdgcn_mfma_f32_16x16x32_bf16(
                            af[mt], bf[nt], acc[mt][nt], 0, 0, 0);
            }
            __syncthreads();
        }
    }
    // ---- epilogue: C layout col=lane&15, row=(lane>>4)*4+reg ; add base_b
    const int rq = fq << 2;
    float bias[4];
    #pragma unroll
    for (int nt = 0; nt < 4; ++nt) bias[nt] = bb[o0 + wn + (nt << 4) + fm];
    #pragma unroll
    for (int mt = 0; mt < 4; ++mt) {
        #pragma unroll
        for (int nt = 0; nt < 4; ++nt) {
            const int gr = n0 + wm + (mt << 4) + rq;
            const int gc = o0 + wn + (nt << 4) + fm;
            #pragma unroll
            for (int r = 0; r < 4; ++r)
                out[(size_t)(gr + r) * DIM + gc] = acc[mt][nt][r] + bias[nt];
        }
    }
}

extern "C" void kernel_launch(void* const* d_in, const int* in_sizes, int n_in,
                              void* d_out, int out_size, void* d_ws, size_t ws_size,
                              hipStream_t stream) {
    const float* x   = (const float*)d_in[0];
    const float* gam = (const float*)d_in[1];
    const float* bet = (const float*)d_in[2];
    const float* sw  = (const float*)d_in[3];
    const float* bwt = (const float*)d_in[4];
    const float* bb  = (const float*)d_in[5];
    float* out = (float*)d_out;

    unsigned short* Bw = (unsigned short*)d_ws;               // 512*8192 bf16 = 8 MB
    unsigned short* xn = Bw + (size_t)DIM * KTOT;             // 32768*512 bf16 = 32 MB

    prep_w_k<<<dim3(512), dim3(256), 0, stream>>>(sw, bwt, Bw);
    prep_xn_k<<<dim3(NROWS / 4), dim3(256), 0, stream>>>(x, gam, bet, xn);
    kan_gemm<<<dim3(512), dim3(512), 0, stream>>>(xn, Bw, x, bb, out);
}

// Round 3
// 385.585 us; speedup vs baseline: 1.2336x; 1.0474x over previous
//
#include <hip/hip_runtime.h>
#include <hip/hip_bf16.h>
#include <stdint.h>

typedef __attribute__((ext_vector_type(8))) short short8;
typedef __attribute__((ext_vector_type(4))) float f32x4;
typedef __attribute__((ext_vector_type(4))) unsigned int u32x4;

#define NROWS 32768
#define DIM 512
#define KTOT 8192
#define KSPL 7680
#define LNEPS 1e-3f
// q = SQL * xn ; basis = exp2(-(q - SQL*grid_g)^2) ; SQL = 3.5*sqrt(log2(e))
#define SQL 4.20392843f

#if __has_builtin(__builtin_amdgcn_exp2f)
#define EXP2F(x) __builtin_amdgcn_exp2f(x)
#else
#define EXP2F(x) exp2f(x)
#endif

__device__ __forceinline__ unsigned short f2bf(float f) {
    unsigned u = __float_as_uint(f);
    u += 0x7fffu + ((u >> 16) & 1u);           // RNE
    return (unsigned short)(u >> 16);
}

// pack two floats -> two bf16 (round-half-up) in one u32 via v_perm
__device__ __forceinline__ unsigned pack_bf2(float a, float b) {
    unsigned ua = __float_as_uint(a) + 0x8000u;
    unsigned ub = __float_as_uint(b) + 0x8000u;
    return __builtin_amdgcn_perm(ub, ua, 0x07060302u); // lo16=ua>>16, hi16=ub>>16
}

// ---------------- prep: weights -> bf16 Bw[o][k], k = g*512+d (spline) | 7680+d (base^T)
// Coalesced global reads AND writes; transpose goes through LDS (stride-15
// float reads -> conflict-free on 32 banks).
__global__ __launch_bounds__(256) void prep_w_k(const float* __restrict__ sw,
                                                const float* __restrict__ bwt,
                                                unsigned short* __restrict__ Bw) {
    __shared__ float lds[KSPL];
    const int o = blockIdx.x;
    const int t = threadIdx.x;
    const float* swr = sw + (size_t)o * KSPL;
    unsigned short* br = Bw + (size_t)o * KTOT;
    #pragma unroll
    for (int it = 0; it < 30; ++it) lds[it * 256 + t] = swr[it * 256 + t];
    #pragma unroll
    for (int it = 0; it < 2; ++it) {
        int d = it * 256 + t;
        br[KSPL + d] = f2bf(bwt[(size_t)d * DIM + o]);
    }
    __syncthreads();
    #pragma unroll
    for (int it = 0; it < 30; ++it) {
        int k = it * 256 + t;              // destination order: k = g*512 + d
        int g = k >> 9, d = k & 511;
        br[k] = f2bf(lds[d * 15 + g]);
    }
}

// ---------------- fused LN + KAN GEMM: out[n][o] = sum_k A[n][k]*Bw[o][k] + bb[o]
// A generated on the fly: k<7680 -> RBF basis of layernorm(x); k>=7680 -> relu(x)
// Block tile 128 rows x 512 cols (R=1: basis computed exactly once), 1024 thr
// (16 waves, wave tile 64x64). Grid 256 = 1 block/CU. LDS 80KB.
__global__ __launch_bounds__(1024, 4) void kan_gemm(
    const float* __restrict__ x,
    const unsigned short* __restrict__ Bw,
    const float* __restrict__ gam,
    const float* __restrict__ bet,
    const float* __restrict__ bb,
    float* __restrict__ out) {
    __shared__ __align__(16) short As[128 * 64];
    __shared__ __align__(16) short Bs[512 * 64];

    const int t = threadIdx.x;
    const int w = t >> 6, l = t & 63;
    const int n0 = blockIdx.x << 7;

    const int ar  = t >> 3;    // A-staging row 0..127 (also LN-stats row)
    const int kkg = t & 7;     // A-staging k-granule
    const int wm = (w >> 3) << 6;            // wave row offset: 0 / 64
    const int wn = (w & 7) << 6;             // wave col offset: 0..448
    const int fm = l & 15, fq = l >> 4;
    const int brow = l >> 3;                 // B staging col-in-8
    const int bxor = (l & 7) ^ brow;         // source k-granule realizing xor swizzle
    const int asto = ((ar << 3) | (kkg ^ (ar & 7))) << 3;  // As store short-index

    // ---- LayerNorm stats for row ar (8 threads/row, shuffle reduce)
    const float* xrow = x + (size_t)(n0 + ar) * DIM;
    float s = 0.f, ss = 0.f;
    #pragma unroll
    for (int it = 0; it < 16; ++it) {
        float4 v = *(const float4*)(xrow + it * 32 + ((t & 7) << 2));
        s  += v.x + v.y + v.z + v.w;
        ss += v.x * v.x + v.y * v.y + v.z * v.z + v.w * v.w;
    }
    #pragma unroll
    for (int m = 4; m >= 1; m >>= 1) {
        s  += __shfl_xor(s,  m, 64);
        ss += __shfl_xor(ss, m, 64);
    }
    const float mean = s * (1.0f / DIM);
    const float rstd = rsqrtf(ss * (1.0f / DIM) - mean * mean + LNEPS);
    const float sr = SQL * rstd;

    f32x4 acc[4][4];
    #pragma unroll
    for (int i = 0; i < 4; ++i)
        #pragma unroll
        for (int j = 0; j < 4; ++j)
            acc[i][j] = (f32x4)0.0f;

    #pragma unroll 1
    for (int dsb = 0; dsb < 8; ++dsb) {
        const int d0 = dsb << 6;
        const int dc = d0 + (kkg << 3);
        // raw x slice (reused for relu) and pre-scaled q = SQL*layernorm(x)
        float xr[8], q[8];
        {
            float4 a = *(const float4*)(xrow + dc);
            float4 b = *(const float4*)(xrow + dc + 4);
            xr[0] = a.x; xr[1] = a.y; xr[2] = a.z; xr[3] = a.w;
            xr[4] = b.x; xr[5] = b.y; xr[6] = b.z; xr[7] = b.w;
            float4 g0 = *(const float4*)(gam + dc);
            float4 g1 = *(const float4*)(gam + dc + 4);
            float4 b0 = *(const float4*)(bet + dc);
            float4 b1 = *(const float4*)(bet + dc + 4);
            float gv[8] = {g0.x, g0.y, g0.z, g0.w, g1.x, g1.y, g1.z, g1.w};
            float bv[8] = {b0.x, b0.y, b0.z, b0.w, b1.x, b1.y, b1.z, b1.w};
            #pragma unroll
            for (int j = 0; j < 8; ++j) {
                float c = sr * gv[j];
                float o = __builtin_fmaf(-mean, c, SQL * bv[j]);
                q[j] = __builtin_fmaf(xr[j], c, o);
            }
        }
        #pragma unroll 1
        for (int g = 0; g < 16; ++g) {
            const int kc = (g < 15) ? ((g << 9) + d0) : (KSPL + d0);
            // ---- B staging: 512x64 bf16 via async DMA (4 x 16KB rounds)
            #pragma unroll
            for (int i = 0; i < 4; ++i) {
                const int rb = (i << 7) + (w << 3);   // wave-uniform
                const unsigned short* gp =
                    Bw + (size_t)(rb + brow) * KTOT + kc + (bxor << 3);
                __builtin_amdgcn_global_load_lds(
                    (const __attribute__((address_space(1))) void*)gp,
                    (__attribute__((address_space(3))) void*)&Bs[rb << 6],
                    16, 0, 0);
            }
            // ---- A staging: basis (or relu) -> bf16 -> LDS (xor-swizzled)
            u32x4 v;
            if (g < 15) {
                const float qg = SQL * (-2.0f + (float)g * (2.0f / 7.0f));
                float e[8];
                #pragma unroll
                for (int j = 0; j < 8; ++j) {
                    float d = q[j] - qg;
                    e[j] = EXP2F(-(d * d));
                }
                v[0] = pack_bf2(e[0], e[1]);
                v[1] = pack_bf2(e[2], e[3]);
                v[2] = pack_bf2(e[4], e[5]);
                v[3] = pack_bf2(e[6], e[7]);
            } else {
                v[0] = pack_bf2(fmaxf(xr[0], 0.f), fmaxf(xr[1], 0.f));
                v[1] = pack_bf2(fmaxf(xr[2], 0.f), fmaxf(xr[3], 0.f));
                v[2] = pack_bf2(fmaxf(xr[4], 0.f), fmaxf(xr[5], 0.f));
                v[3] = pack_bf2(fmaxf(xr[6], 0.f), fmaxf(xr[7], 0.f));
            }
            *(u32x4*)&As[asto] = v;
            __syncthreads();
            // ---- MFMA: 2 k-steps of 32, 4x4 tiles of 16x16 (wave 64x64)
            #pragma unroll
            for (int ks = 0; ks < 2; ++ks) {
                const int kg = (ks << 2) + fq;
                short8 af[4], bfr[4];
                #pragma unroll
                for (int mt = 0; mt < 4; ++mt) {
                    const int m = wm + (mt << 4) + fm;
                    af[mt] = *(const short8*)&As[((m << 3) | (kg ^ (m & 7))) << 3];
                }
                #pragma unroll
                for (int nt = 0; nt < 4; ++nt) {
                    const int n = wn + (nt << 4) + fm;
                    bfr[nt] = *(const short8*)&Bs[((n << 3) | (kg ^ (n & 7))) << 3];
                }
                #pragma unroll
                for (int mt = 0; mt < 4; ++mt)
                    #pragma unroll
                    for (int nt = 0; nt < 4; ++nt)
                        acc[mt][nt] = __builtin_amdgcn_mfma_f32_16x16x32_bf16(
                            af[mt], bfr[nt], acc[mt][nt], 0, 0, 0);
            }
            __syncthreads();
        }
    }
    // ---- epilogue: C layout col=lane&15, row=(lane>>4)*4+reg ; add base_b
    const int rq = fq << 2;
    float bias[4];
    #pragma unroll
    for (int nt = 0; nt < 4; ++nt) bias[nt] = bb[wn + (nt << 4) + fm];
    #pragma unroll
    for (int mt = 0; mt < 4; ++mt) {
        #pragma unroll
        for (int nt = 0; nt < 4; ++nt) {
            const int gr = n0 + wm + (mt << 4) + rq;
            const int gc = wn + (nt << 4) + fm;
            #pragma unroll
            for (int r = 0; r < 4; ++r)
                out[(size_t)(gr + r) * DIM + gc] = acc[mt][nt][r] + bias[nt];
        }
    }
}

extern "C" void kernel_launch(void* const* d_in, const int* in_sizes, int n_in,
                              void* d_out, int out_size, void* d_ws, size_t ws_size,
                              hipStream_t stream) {
    const float* x   = (const float*)d_in[0];
    const float* gam = (const float*)d_in[1];
    const float* bet = (const float*)d_in[2];
    const float* sw  = (const float*)d_in[3];
    const float* bwt = (const float*)d_in[4];
    const float* bb  = (const float*)d_in[5];
    float* out = (float*)d_out;

    unsigned short* Bw = (unsigned short*)d_ws;   // 512*8192 bf16 = 8 MB

    prep_w_k<<<dim3(512), dim3(256), 0, stream>>>(sw, bwt, Bw);
    kan_gemm<<<dim3(256), dim3(1024), 0, stream>>>(x, Bw, gam, bet, bb, out);
}